// Round 1
// baseline (237.304 us; speedup 1.0000x reference)
//
#include <hip/hip_runtime.h>

// Problem constants (from reference)
#define BATCH 4
#define POINT_NUM 50000
#define NPTS (BATCH * POINT_NUM)   // 200000
#define FEAT 256

// One wave (64 lanes) per point: lane l loads float4 of the gathered row at
// elements [4l, 4l+4) plus the matching weight float4s, computes the two
// partial dots, butterfly-reduces across 64 lanes, lane 0 writes 2 scalars.
__global__ __launch_bounds__(256) void suction_kernel(
    const float* __restrict__ feat,   // [N_VOXELS, FEAT]
    const int*   __restrict__ idx,    // [NPTS]
    const float* __restrict__ w,      // [2, FEAT]
    const float* __restrict__ bias,   // [2]
    float*       __restrict__ out)    // [2, NPTS] (seal flat, then wrench flat)
{
    const int gtid = blockIdx.x * blockDim.x + threadIdx.x;
    const int wave = gtid >> 6;          // global wave id == point id
    const int lane = threadIdx.x & 63;
    if (wave >= NPTS) return;

    // Weights: lane l owns features [4l, 4l+4). Tiny, L2-resident.
    const float4 w0 = ((const float4*)(w))[lane];
    const float4 w1 = ((const float4*)(w + FEAT))[lane];

    const int v = idx[wave];
    const float4 f = ((const float4*)(feat + (long long)v * FEAT))[lane];

    float s0 = f.x * w0.x + f.y * w0.y + f.z * w0.z + f.w * w0.w;
    float s1 = f.x * w1.x + f.y * w1.y + f.z * w1.z + f.w * w1.w;

    // Butterfly reduction across the 64-lane wave (CDNA wave = 64).
    #pragma unroll
    for (int off = 32; off > 0; off >>= 1) {
        s0 += __shfl_down(s0, off, 64);
        s1 += __shfl_down(s1, off, 64);
    }

    if (lane == 0) {
        out[wave]        = s0 + bias[0];
        out[NPTS + wave] = s1 + bias[1];
    }
}

extern "C" void kernel_launch(void* const* d_in, const int* in_sizes, int n_in,
                              void* d_out, int out_size, void* d_ws, size_t ws_size,
                              hipStream_t stream) {
    const float* feat = (const float*)d_in[0];
    const int*   idx  = (const int*)d_in[1];
    const float* w    = (const float*)d_in[2];
    const float* bias = (const float*)d_in[3];
    float* out = (float*)d_out;

    // 200000 waves, 4 waves per 256-thread block -> 50000 blocks
    const int blocks = (NPTS * 64 + 255) / 256;
    suction_kernel<<<blocks, 256, 0, stream>>>(feat, idx, w, bias, out);
}

// Round 2
// 215.673 us; speedup vs baseline: 1.1003x; 1.1003x over previous
//
#include <hip/hip_runtime.h>

// Problem constants (from reference)
#define BATCH 4
#define POINT_NUM 50000
#define NPTS (BATCH * POINT_NUM)   // 200000
#define NVOX 150000
#define FEAT 256

// Pass 1: project ALL voxels through the 2x256 linear layer.
// One wave (64 lanes) per voxel row: lane l loads float4 at [4l,4l+4),
// computes both partial dots, butterfly-reduces, lane 0 writes 2 scalars.
// Reads are fully sequential (consecutive waves -> consecutive rows), so
// this streams at HBM BW instead of random-gather BW.
__global__ __launch_bounds__(256) void project_kernel(
    const float* __restrict__ feat,   // [NVOX, FEAT]
    const float* __restrict__ w,      // [2, FEAT]
    const float* __restrict__ bias,   // [2]
    float* __restrict__ s0,           // [NVOX] scratch
    float* __restrict__ s1)           // [NVOX] scratch
{
    const int wave = (blockIdx.x * blockDim.x + threadIdx.x) >> 6;
    const int lane = threadIdx.x & 63;
    if (wave >= NVOX) return;

    const float4 w0 = ((const float4*)(w))[lane];
    const float4 w1 = ((const float4*)(w + FEAT))[lane];
    const float4 f  = ((const float4*)(feat + (size_t)wave * FEAT))[lane];

    float a = f.x * w0.x + f.y * w0.y + f.z * w0.z + f.w * w0.w;
    float b = f.x * w1.x + f.y * w1.y + f.z * w1.z + f.w * w1.w;

    #pragma unroll
    for (int off = 32; off > 0; off >>= 1) {
        a += __shfl_down(a, off, 64);
        b += __shfl_down(b, off, 64);
    }

    if (lane == 0) {
        s0[wave] = a + bias[0];
        s1[wave] = b + bias[1];
    }
}

// Pass 2: per-point gather of the 2 projected scores. The score tables are
// 600 KB each -> L2-resident; random 4B reads are cheap here.
__global__ __launch_bounds__(256) void gather_kernel(
    const int* __restrict__ idx,      // [NPTS]
    const float* __restrict__ s0,
    const float* __restrict__ s1,
    float* __restrict__ out)          // [2, NPTS]
{
    const int p = blockIdx.x * blockDim.x + threadIdx.x;
    if (p >= NPTS) return;
    const int v = idx[p];
    out[p]        = s0[v];
    out[NPTS + p] = s1[v];
}

extern "C" void kernel_launch(void* const* d_in, const int* in_sizes, int n_in,
                              void* d_out, int out_size, void* d_ws, size_t ws_size,
                              hipStream_t stream) {
    const float* feat = (const float*)d_in[0];
    const int*   idx  = (const int*)d_in[1];
    const float* w    = (const float*)d_in[2];
    const float* bias = (const float*)d_in[3];
    float* out = (float*)d_out;

    float* s0 = (float*)d_ws;          // [NVOX]
    float* s1 = s0 + NVOX;             // [NVOX]  (1.2 MB total, ws is plenty)

    // 150000 waves, 4 waves per 256-thread block
    const int blocks1 = (NVOX * 64 + 255) / 256;
    project_kernel<<<blocks1, 256, 0, stream>>>(feat, w, bias, s0, s1);

    const int blocks2 = (NPTS + 255) / 256;
    gather_kernel<<<blocks2, 256, 0, stream>>>(idx, s0, s1, out);
}